// Round 1
// baseline (96.474 us; speedup 1.0000x reference)
//
#include <hip/hip_runtime.h>

// RetinaNetFocalLoss on MI355X.
// Inputs (dict order): clas_preds (16,49152,80) f32, bbox_preds (16,49152,4) f32,
//                      bbox_tgts (16,64,4) f32 tlbr, clas_tgts (16,64) i32, anchors (49152,4) f32 cthw.
// Output: single f32 scalar.
//
// Structure: one fused kernel (matching + huber + focal) producing per-block
// undivided partials {bb_sum, focal_sum, m_count}; deterministic finalize kernel
// applies per-image max(m,1)/max(4m,1) divisors and averages over B.

#define A_CNT 49152
#define T_CNT 64
#define C_CNT 80
#define ABLK  256
#define NBLK  (A_CNT / ABLK)   // 192
#define B_CNT 16

__global__ __launch_bounds__(ABLK) void rnfl_main(
    const float* __restrict__ clas_preds,
    const float* __restrict__ bbox_preds,
    const float* __restrict__ bbox_tgts,
    const int*   __restrict__ clas_tgts,
    const float* __restrict__ anchors,
    float* __restrict__ bb_part,
    float* __restrict__ fl_part,
    int*   __restrict__ m_part)
{
    const int tid = threadIdx.x;
    const int b   = blockIdx.y;
    const int a0  = blockIdx.x * ABLK;

    // Target staging: tlbr (roundtripped through cthw like the reference), area, cthw, class.
    __shared__ float tx1[T_CNT], ty1[T_CNT], tx2[T_CNT], ty2[T_CNT];
    __shared__ float tar[T_CNT];
    __shared__ float tcx[T_CNT], tcy[T_CNT], tswx[T_CNT], tswy[T_CNT];
    __shared__ int   tcl[T_CNT];
    __shared__ int   codes[ABLK];   // -2 excluded, -1 background, 0..79 hot class
    __shared__ float rbb[4], rfl[4];
    __shared__ int   rmm[4];

    if (tid < T_CNT) {
        float4 bt = reinterpret_cast<const float4*>(bbox_tgts)[b * T_CNT + tid];
        // tlbr -> cthw (reference: tlbr2cthw)
        float cx = (bt.x + bt.z) * 0.5f;
        float cy = (bt.y + bt.w) * 0.5f;
        float sx = bt.z - bt.x;
        float sy = bt.w - bt.y;
        tcx[tid] = cx; tcy[tid] = cy; tswx[tid] = sx; tswy[tid] = sy;
        // cthw -> tlbr again (reference: iou_cthw converts back)
        tx1[tid] = cx - sx * 0.5f;
        ty1[tid] = cy - sy * 0.5f;
        tx2[tid] = cx + sx * 0.5f;
        ty2[tid] = cy + sy * 0.5f;
        tar[tid] = sx * sy;
        tcl[tid] = clas_tgts[b * T_CNT + tid];
    }
    __syncthreads();

    // ---- Phase 1: matching + huber (one anchor per thread) ----
    const int a = a0 + tid;
    float4 anc = reinterpret_cast<const float4*>(anchors)[a];
    const float ax1 = anc.x - anc.z * 0.5f;
    const float ay1 = anc.y - anc.w * 0.5f;
    const float ax2 = anc.x + anc.z * 0.5f;
    const float ay2 = anc.y + anc.w * 0.5f;
    const float areaA = anc.z * anc.w;

    // Track argmax of inter/den via cross-multiplication (avoids 64 divisions).
    float bn = -1.0f, bd = 1.0f;   // best numerator / denominator
    int   bj = 0;
#pragma unroll 8
    for (int j = 0; j < T_CNT; ++j) {
        float ix1 = fmaxf(ax1, tx1[j]);
        float iy1 = fmaxf(ay1, ty1[j]);
        float ix2 = fminf(ax2, tx2[j]);
        float iy2 = fminf(ay2, ty2[j]);
        float w = fmaxf(ix2 - ix1, 0.0f);
        float h = fmaxf(iy2 - iy1, 0.0f);
        float inter = w * h;
        float den = areaA + tar[j] - inter + 1e-8f;
        // strict > keeps the FIRST max (matches jnp.argmax)
        if (inter * bd > bn * den) { bn = inter; bd = den; bj = j; }
    }
    const float iou = bn / bd;

    int   code;
    float bb   = 0.0f;
    int   mloc = 0;
    if (iou > 0.5f) {
        mloc = 1;
        code = tcl[bj] - 1;            // hot class in [0,79]
        float4 bp = reinterpret_cast<const float4*>(bbox_preds)[(size_t)b * A_CNT + a];
        float t0 = ((tcx[bj] - anc.x) / anc.z) / 0.1f;
        float t1 = ((tcy[bj] - anc.y) / anc.w) / 0.1f;
        float t2 = logf(tswx[bj] / anc.z + 1e-8f) / 0.2f;
        float t3 = logf(tswy[bj] / anc.w + 1e-8f) / 0.2f;
        float d, ad;
        d = bp.x - t0; ad = fabsf(d); bb += (ad < 1.0f) ? 0.5f * d * d : ad - 0.5f;
        d = bp.y - t1; ad = fabsf(d); bb += (ad < 1.0f) ? 0.5f * d * d : ad - 0.5f;
        d = bp.z - t2; ad = fabsf(d); bb += (ad < 1.0f) ? 0.5f * d * d : ad - 0.5f;
        d = bp.w - t3; ad = fabsf(d); bb += (ad < 1.0f) ? 0.5f * d * d : ad - 0.5f;
    } else {
        code = (iou < 0.4f) ? -1 : -2;
    }
    codes[tid] = code;
    __syncthreads();

    // ---- Phase 2: focal loss, coalesced float4 sweep over this block's 256x80 slab ----
    float fl = 0.0f;
    const float4* cp4 = reinterpret_cast<const float4*>(
        clas_preds + ((size_t)b * A_CNT + a0) * C_CNT);
#pragma unroll 4
    for (int i = 0; i < (ABLK * C_CNT / 4) / ABLK; ++i) {   // 20 iterations
        int f  = i * ABLK + tid;                // float4 index within slab
        int al = (unsigned)f / 20u;             // local anchor (80 floats = 20 float4)
        int c0 = (f - al * 20) * 4;             // first class of this float4
        int cc = codes[al];
        float4 v = cp4[f];
        if (cc != -2) {
            const float* vp = reinterpret_cast<const float*>(&v);
#pragma unroll
            for (int k = 0; k < 4; ++k) {
                float x  = vp[k];
                float e  = __expf(-fabsf(x));           // exp(-|x|)
                float l  = __logf(1.0f + e);            // log1p(e), e >= exp(-~6)
                float sp = fmaxf(x, 0.0f) + l;          // softplus(x)
                float inv = __builtin_amdgcn_rcpf(1.0f + e);
                float ps  = (x >= 0.0f) ? inv : e * inv;   // sigmoid(x)
                float psn = (x >= 0.0f) ? e * inv : inv;   // sigmoid(-x) = 1-ps
                bool hot = ((c0 + k) == cc);
                float pt  = hot ? psn : ps;
                float af  = hot ? 0.75f : 0.25f;
                float bce = hot ? (sp - x) : sp;           // softplus(-x) = softplus(x)-x
                fl += pt * pt * af * bce;
            }
        }
    }

    // ---- Block reduction (4 waves of 64) ----
#pragma unroll
    for (int off = 32; off > 0; off >>= 1) {
        bb   += __shfl_down(bb, off);
        fl   += __shfl_down(fl, off);
        mloc += __shfl_down(mloc, off);
    }
    const int wave = tid >> 6, lane = tid & 63;
    if (lane == 0) { rbb[wave] = bb; rfl[wave] = fl; rmm[wave] = mloc; }
    __syncthreads();
    if (tid == 0) {
        float Bs = rbb[0] + rbb[1] + rbb[2] + rbb[3];
        float Fs = rfl[0] + rfl[1] + rfl[2] + rfl[3];
        int   Ms = rmm[0] + rmm[1] + rmm[2] + rmm[3];
        int slot = b * NBLK + blockIdx.x;
        bb_part[slot] = Bs;
        fl_part[slot] = Fs;
        m_part[slot]  = Ms;
    }
}

__global__ __launch_bounds__(NBLK) void rnfl_final(
    const float* __restrict__ bb_part,
    const float* __restrict__ fl_part,
    const int*   __restrict__ m_part,
    float* __restrict__ out)
{
    const int tid = threadIdx.x;          // 192 threads = 3 waves
    const int lane = tid & 63, wave = tid >> 6;
    __shared__ float rb[3], rf[3];
    __shared__ int   rm[3];
    __shared__ double stot;
    if (tid == 0) stot = 0.0;
    __syncthreads();

    for (int b = 0; b < B_CNT; ++b) {
        float bb = bb_part[b * NBLK + tid];
        float fl = fl_part[b * NBLK + tid];
        int   m  = m_part[b * NBLK + tid];
#pragma unroll
        for (int off = 32; off > 0; off >>= 1) {
            bb += __shfl_down(bb, off);
            fl += __shfl_down(fl, off);
            m  += __shfl_down(m, off);
        }
        if (lane == 0) { rb[wave] = bb; rf[wave] = fl; rm[wave] = m; }
        __syncthreads();
        if (tid == 0) {
            float Bs = rb[0] + rb[1] + rb[2];
            float Fs = rf[0] + rf[1] + rf[2];
            int   Ms = rm[0] + rm[1] + rm[2];
            float mf = (float)Ms;
            stot += (double)(Bs / fmaxf(mf * 4.0f, 1.0f))
                  + (double)(Fs / fmaxf(mf, 1.0f));
        }
        __syncthreads();
    }
    if (tid == 0) out[0] = (float)(stot / (double)B_CNT);
}

extern "C" void kernel_launch(void* const* d_in, const int* in_sizes, int n_in,
                              void* d_out, int out_size, void* d_ws, size_t ws_size,
                              hipStream_t stream)
{
    const float* clas_preds = (const float*)d_in[0];
    const float* bbox_preds = (const float*)d_in[1];
    const float* bbox_tgts  = (const float*)d_in[2];
    const int*   clas_tgts  = (const int*)d_in[3];
    const float* anchors    = (const float*)d_in[4];
    float* out = (float*)d_out;

    float* bb_part = (float*)d_ws;
    float* fl_part = bb_part + B_CNT * NBLK;
    int*   m_part  = (int*)(fl_part + B_CNT * NBLK);

    dim3 grid(NBLK, B_CNT);
    rnfl_main<<<grid, ABLK, 0, stream>>>(clas_preds, bbox_preds, bbox_tgts,
                                         clas_tgts, anchors,
                                         bb_part, fl_part, m_part);
    rnfl_final<<<1, NBLK, 0, stream>>>(bb_part, fl_part, m_part, out);
}

// Round 2
// 80.643 us; speedup vs baseline: 1.1963x; 1.1963x over previous
//
#include <hip/hip_runtime.h>

// RetinaNetFocalLoss on MI355X (gfx950).
// Inputs: clas_preds (16,49152,80) f32, bbox_preds (16,49152,4) f32,
//         bbox_tgts (16,64,4) f32 tlbr, clas_tgts (16,64) i32, anchors (49152,4) f32 cthw.
// Output: single f32 scalar.
//
// v2: packed float4 LDS targets (1 ds_read_b128/IoU iter instead of 5 b32),
//     division-free matching (cross-multiplied argmax + thresholds),
//     focal computed all-non-hot (exp-form: 3 trans + ~6 VALU per element)
//     with a rare per-float4 hot-correction branch, single-pass finalize.

#define A_CNT 49152
#define T_CNT 64
#define C_CNT 80
#define ABLK  256
#define NBLK  (A_CNT / ABLK)   // 192
#define B_CNT 16

__global__ __launch_bounds__(ABLK) void rnfl_main(
    const float* __restrict__ clas_preds,
    const float* __restrict__ bbox_preds,
    const float* __restrict__ bbox_tgts,
    const int*   __restrict__ clas_tgts,
    const float* __restrict__ anchors,
    float* __restrict__ bb_part,
    float* __restrict__ fl_part,
    int*   __restrict__ m_part)
{
    const int tid = threadIdx.x;
    const int b   = blockIdx.y;
    const int a0  = blockIdx.x * ABLK;

    __shared__ float4 tbox[T_CNT];   // target tlbr (roundtripped thru cthw like ref)
    __shared__ int    tcl[T_CNT];
    __shared__ int    codes[ABLK];   // -2 excluded, -1 background, 0..79 hot class
    __shared__ float  rbb[4], rfl[4];
    __shared__ int    rmm[4];

    if (tid < T_CNT) {
        float4 bt = reinterpret_cast<const float4*>(bbox_tgts)[b * T_CNT + tid];
        // tlbr -> cthw -> tlbr (reference roundtrip)
        float cx = (bt.x + bt.z) * 0.5f;
        float cy = (bt.y + bt.w) * 0.5f;
        float sx = bt.z - bt.x;
        float sy = bt.w - bt.y;
        float4 tb;
        tb.x = cx - sx * 0.5f;
        tb.y = cy - sy * 0.5f;
        tb.z = cx + sx * 0.5f;
        tb.w = cy + sy * 0.5f;
        tbox[tid] = tb;
        tcl[tid]  = clas_tgts[b * T_CNT + tid];
    }
    __syncthreads();

    // ---- Phase 1: matching + huber (one anchor per thread), division-free ----
    const int a = a0 + tid;
    float4 anc = reinterpret_cast<const float4*>(anchors)[a];
    const float ax1 = anc.x - anc.z * 0.5f;
    const float ay1 = anc.y - anc.w * 0.5f;
    const float ax2 = anc.x + anc.z * 0.5f;
    const float ay2 = anc.y + anc.w * 0.5f;
    const float areaA = anc.z * anc.w;

    float bn = -1.0f, bd = 1.0f;   // best numerator / denominator
    int   bj = 0;
#pragma unroll 8
    for (int j = 0; j < T_CNT; ++j) {
        float4 tb = tbox[j];                 // wave-uniform broadcast b128
        float ix1 = fmaxf(ax1, tb.x);
        float iy1 = fmaxf(ay1, tb.y);
        float ix2 = fminf(ax2, tb.z);
        float iy2 = fminf(ay2, tb.w);
        float w = fmaxf(ix2 - ix1, 0.0f);
        float h = fmaxf(iy2 - iy1, 0.0f);
        float inter = w * h;
        float den = areaA + (tb.z - tb.x) * (tb.w - tb.y) - inter + 1e-8f;
        // strict > keeps FIRST max (matches jnp.argmax); den > 0 always
        if (inter * bd > bn * den) { bn = inter; bd = den; bj = j; }
    }

    int   code;
    float bb   = 0.0f;
    int   mloc = 0;
    if (bn > 0.5f * bd) {                    // iou > MATCH_THR
        mloc = 1;
        code = tcl[bj] - 1;                  // hot class in [0,79]
        float4 tb = tbox[bj];
        float gx = (tb.x + tb.z) * 0.5f;
        float gy = (tb.y + tb.w) * 0.5f;
        float gw = tb.z - tb.x;
        float gh = tb.w - tb.y;
        float4 bp = reinterpret_cast<const float4*>(bbox_preds)[(size_t)b * A_CNT + a];
        float t0 = ((gx - anc.x) / anc.z) * 10.0f;           // / SCALE 0.1
        float t1 = ((gy - anc.y) / anc.w) * 10.0f;
        float t2 = __logf(gw / anc.z + 1e-8f) * 5.0f;        // / SCALE 0.2
        float t3 = __logf(gh / anc.w + 1e-8f) * 5.0f;
        float d, ad;
        d = bp.x - t0; ad = fabsf(d); bb += (ad < 1.0f) ? 0.5f * d * d : ad - 0.5f;
        d = bp.y - t1; ad = fabsf(d); bb += (ad < 1.0f) ? 0.5f * d * d : ad - 0.5f;
        d = bp.z - t2; ad = fabsf(d); bb += (ad < 1.0f) ? 0.5f * d * d : ad - 0.5f;
        d = bp.w - t3; ad = fabsf(d); bb += (ad < 1.0f) ? 0.5f * d * d : ad - 0.5f;
    } else {
        code = (bn < 0.4f * bd) ? -1 : -2;   // background vs excluded
    }
    codes[tid] = code;
    __syncthreads();

    // ---- Phase 2: focal, coalesced float4 sweep; all-non-hot + rare hot fix ----
    float fl = 0.0f;
    const float4* cp4 = reinterpret_cast<const float4*>(
        clas_preds + ((size_t)b * A_CNT + a0) * C_CNT);
#pragma unroll 4
    for (int i = 0; i < 20; ++i) {
        int f  = i * ABLK + tid;
        int al = (unsigned)f / 20u;          // local anchor (80 floats = 20 float4)
        int c0 = (f - al * 20) * 4;          // first class index of this float4
        int cc = codes[al];
        float4 v = cp4[f];

        // non-hot contribution: 0.25 * sigmoid(x)^2 * softplus(x)
        float s4 = 0.0f;
        {
            float e = __expf(v.x); float t = 1.0f + e;
            float inv = __builtin_amdgcn_rcpf(t);
            float ps = e * inv; float sp = __logf(t);
            s4 = fmaf(ps * ps, sp, s4);
        }
        {
            float e = __expf(v.y); float t = 1.0f + e;
            float inv = __builtin_amdgcn_rcpf(t);
            float ps = e * inv; float sp = __logf(t);
            s4 = fmaf(ps * ps, sp, s4);
        }
        {
            float e = __expf(v.z); float t = 1.0f + e;
            float inv = __builtin_amdgcn_rcpf(t);
            float ps = e * inv; float sp = __logf(t);
            s4 = fmaf(ps * ps, sp, s4);
        }
        {
            float e = __expf(v.w); float t = 1.0f + e;
            float inv = __builtin_amdgcn_rcpf(t);
            float ps = e * inv; float sp = __logf(t);
            s4 = fmaf(ps * ps, sp, s4);
        }
        float maskf = (cc >= -1) ? 0.25f : 0.0f;   // cc==-2 excluded
        fl = fmaf(maskf, s4, fl);

        // rare: this float4 holds the matched anchor's hot class
        if (cc >= c0 && cc < c0 + 4) {
            float x = (cc == c0)     ? v.x
                    : (cc == c0 + 1) ? v.y
                    : (cc == c0 + 2) ? v.z
                    :                  v.w;
            float e = __expf(x); float t = 1.0f + e;
            float inv = __builtin_amdgcn_rcpf(t);
            float ps = e * inv; float q = 1.0f - ps;
            float sp = __logf(t);
            // replace 0.25*ps^2*sp with 0.75*(1-ps)^2*softplus(-x); softplus(-x)=sp-x
            fl += 0.75f * q * q * (sp - x) - 0.25f * ps * ps * sp;
        }
    }

    // ---- Block reduction (4 waves of 64) ----
#pragma unroll
    for (int off = 32; off > 0; off >>= 1) {
        bb   += __shfl_down(bb, off);
        fl   += __shfl_down(fl, off);
        mloc += __shfl_down(mloc, off);
    }
    const int wave = tid >> 6, lane = tid & 63;
    if (lane == 0) { rbb[wave] = bb; rfl[wave] = fl; rmm[wave] = mloc; }
    __syncthreads();
    if (tid == 0) {
        int slot = b * NBLK + blockIdx.x;
        bb_part[slot] = rbb[0] + rbb[1] + rbb[2] + rbb[3];
        fl_part[slot] = rfl[0] + rfl[1] + rfl[2] + rfl[3];
        m_part[slot]  = rmm[0] + rmm[1] + rmm[2] + rmm[3];
    }
}

// Single-pass finalize: wave w reduces images w, w+4, w+8, w+12.
__global__ __launch_bounds__(256) void rnfl_final(
    const float* __restrict__ bb_part,
    const float* __restrict__ fl_part,
    const int*   __restrict__ m_part,
    float* __restrict__ out)
{
    const int tid = threadIdx.x, lane = tid & 63, wave = tid >> 6;
    __shared__ float wacc[4];
    float lacc = 0.0f;

    for (int img = wave; img < B_CNT; img += 4) {
        float bb = 0.0f, fl = 0.0f; int m = 0;
#pragma unroll
        for (int s = 0; s < 3; ++s) {        // 3*64 = 192 = NBLK
            int idx = img * NBLK + s * 64 + lane;
            bb += bb_part[idx];
            fl += fl_part[idx];
            m  += m_part[idx];
        }
#pragma unroll
        for (int off = 32; off > 0; off >>= 1) {
            bb += __shfl_down(bb, off);
            fl += __shfl_down(fl, off);
            m  += __shfl_down(m, off);
        }
        if (lane == 0) {
            float mf = (float)m;
            lacc += bb / fmaxf(mf * 4.0f, 1.0f) + fl / fmaxf(mf, 1.0f);
        }
    }
    if (lane == 0) wacc[wave] = lacc;
    __syncthreads();
    if (tid == 0)
        out[0] = (wacc[0] + wacc[1] + wacc[2] + wacc[3]) / (float)B_CNT;
}

extern "C" void kernel_launch(void* const* d_in, const int* in_sizes, int n_in,
                              void* d_out, int out_size, void* d_ws, size_t ws_size,
                              hipStream_t stream)
{
    const float* clas_preds = (const float*)d_in[0];
    const float* bbox_preds = (const float*)d_in[1];
    const float* bbox_tgts  = (const float*)d_in[2];
    const int*   clas_tgts  = (const int*)d_in[3];
    const float* anchors    = (const float*)d_in[4];
    float* out = (float*)d_out;

    float* bb_part = (float*)d_ws;
    float* fl_part = bb_part + B_CNT * NBLK;
    int*   m_part  = (int*)(fl_part + B_CNT * NBLK);

    dim3 grid(NBLK, B_CNT);
    rnfl_main<<<grid, ABLK, 0, stream>>>(clas_preds, bbox_preds, bbox_tgts,
                                         clas_tgts, anchors,
                                         bb_part, fl_part, m_part);
    rnfl_final<<<1, 256, 0, stream>>>(bb_part, fl_part, m_part, out);
}